// Round 14
// baseline (775.284 us; speedup 1.0000x reference)
//
#include <hip/hip_runtime.h>

// RealNVP forward, fused across all 8 coupling layers.  Round 21.
// B=131072, D=64, H=256, L=8. out = y[B*D] ++ logdet[B], fp32.
//
// R20 (champion, 775us): packed-state mm3 halving.  Counters: VALU 40.6 /
// MFMA 19.8 / conflicts 4.46e7 / clean regs.  VALU (tanh-dominated) is
// the largest busy pipe; 40% is stall that 6 structural attempts failed
// to move.  Session law: only work removal pays.
//
// R21 = R20 + SCALE FOLDING (strength-reduce the tanh chain):
//  - tanh input is always affine in MFMA output -> fold x*2log2e into
//    the weights/biases at cvt time: W1s/t, b1s/t, (W2+I)s/t, b2s/t,
//    W3s, b3s all pre-scaled by 2log2e (NOT W3t/b3t -- linear use).
//    tanh_pre(z) = 1 - 2*rcp(exp2(z)+1): the per-tanh mul is GONE
//    (~2.1K muls/thread removed).
//  - ep3: scl pre-scaled by log2e in ws -> e = exp2(s3r) directly;
//    logdet accumulated in log2 domain, single *ln2 at the final write.
//  - biases/scl staged pre-scaled as fp32 in ws (34 KB); all cvt work
//    merged into ONE kernel (one launch instead of two).
// Everything else identical to R20: parity-packed W1 (mm1 K=32), W2+I
// fold, row-parity-packed W3 + parity-split state, xm stride 40, s3 in
// regs, setprio, launch_bounds(256,3), 8-barrier fat-phase schedule.

#define BATCH    131072
#define DIM      64
#define HID      256
#define NLAYER   8
#define BM       64
#define NTHREADS 256

#define ACT_S  264   // act row stride, halfs (256 + 8)
#define XMP_S  40    // xm packed row stride, halfs (32 data + 8 pad, 80B rows)

typedef _Float16 f16;
typedef __attribute__((ext_vector_type(8))) _Float16 f16x8;
typedef __attribute__((ext_vector_type(4))) _Float16 f16x4;
typedef __attribute__((ext_vector_type(2))) _Float16 f16x2;
typedef __attribute__((ext_vector_type(4))) float    f32x4;

#define TWO_LOG2E 2.8853900817779268f   // 2*log2(e)
#define LOG2E     1.4426950408889634f
#define LN2       0.6931471805599453f

// tanh with the 2log2e scale PRE-FOLDED into the operand:
// z = 2*log2(e)*x  ->  tanh(x) = 1 - 2/(2^z + 1).  No mul.
__device__ __forceinline__ float tanh_pre(float z) {
  float e = __builtin_amdgcn_exp2f(z);
  return 1.f - 2.f * __builtin_amdgcn_rcpf(e + 1.f);
}

__device__ __forceinline__ f16x2 pk2(float a, float b) {
  return __builtin_bit_cast(f16x2, __builtin_amdgcn_cvt_pkrtz(a, b));
}

// Pack 4 f32 -> f16x4 with two v_cvt_pkrtz_f16_f32.
__device__ __forceinline__ f16x4 pk4(float a, float b, float c, float d) {
  f16x2 lo = pk2(a, b);
  f16x2 hi = pk2(c, d);
  f16x4 o; o[0] = lo[0]; o[1] = lo[1]; o[2] = hi[0]; o[3] = hi[1];
  return o;
}

// One-shot weight/bias conversion.  Ranges (369,664 work items):
//   [0,262144)        W2 s/t: +I, x2log2e, fp16
//   [262144,327680)   W1p s/t: column-parity-pack, x2log2e, fp16
//   [327680,360448)   W3p s/t: row-parity-pack; s x2log2e, t x1, fp16
//   [360448,369664)   biases (x2log2e) + scl (xlog2e), fp32 -> bws
__global__ void cvt_all_kernel(
    const float* sW1f, const float* sW2f, const float* sW3f,
    const float* tW1f, const float* tW2f, const float* tW3f,
    const float* sb1, const float* sb2, const float* sb3,
    const float* tb1, const float* tb2, const float* scl,
    f16* wS1p, f16* wS2, f16* wS3p,
    f16* wT1p, f16* wT2, f16* wT3p, float* bws)
{
  const float S = TWO_LOG2E;
  int i = blockIdx.x * blockDim.x + threadIdx.x;
  if (i < 262144) {
    // W2' = (W2 + I) * S
    const float* s = (i < 131072) ? sW2f : tW2f;
    f16*         d = (i < 131072) ? wS2  : wT2;
    int k = i & 131071;
    float4 v = ((const float4*)s)[k];
    const int row = (k >> 6) & 255;
    const int j0  = (k & 63) * 4;
    const int dr  = row - j0;
    if      (dr == 0) v.x += 1.f;
    else if (dr == 1) v.y += 1.f;
    else if (dr == 2) v.z += 1.f;
    else if (dr == 3) v.w += 1.f;
    ((f16x4*)d)[k] = pk4(v.x * S, v.y * S, v.z * S, v.w * S);
  } else if (i < 327680) {
    // W1p[l][h][k] = W1[l][h][2k + (l&1)] * S
    int j = i - 262144;
    const float* s = (j < 32768) ? sW1f : tW1f;
    f16*         d = (j < 32768) ? wS1p : wT1p;
    j &= 32767;
    int l   = j >> 12;
    int rem = j & 4095;
    int h   = rem >> 4;
    int kq  = rem & 15;
    int par = l & 1;
    const float a = s[l * 16384 + h * 64 + 4 * kq + par];
    const float b = s[l * 16384 + h * 64 + 4 * kq + 2 + par];
    ((f16x2*)d)[j] = pk2(a * S, b * S);
  } else if (i < 360448) {
    // W3p[l][j][k] = W3[l][2j + 1-(l&1)][k] * (s-net: S, t-net: 1)
    int k = i - 327680;
    const bool is_s = (k < 16384);
    const float* s = is_s ? sW3f : tW3f;
    f16*         d = is_s ? wS3p : wT3p;
    const float sc = is_s ? S : 1.f;
    int j2  = k & 16383;
    int l   = j2 >> 11;
    int rem = j2 & 2047;
    int j   = rem >> 6;
    int kq  = rem & 63;
    int dd  = 2 * j + 1 - (l & 1);
    float4 v = ((const float4*)s)[l * 4096 + dd * 64 + kq];
    ((f16x4*)d)[j2] = pk4(v.x * sc, v.y * sc, v.z * sc, v.w * sc);
  } else {
    // bws: [0,2048) b1s*S, [2048,4096) b1t*S, [4096,6144) b2s*S,
    //      [6144,8192) b2t*S, [8192,8704) b3s*S, [8704,9216) scl*log2e
    int k = i - 360448;
    float v;
    if      (k < 2048) v = sb1[k]        * S;
    else if (k < 4096) v = tb1[k - 2048] * S;
    else if (k < 6144) v = sb2[k - 4096] * S;
    else if (k < 8192) v = tb2[k - 6144] * S;
    else if (k < 8704) v = sb3[k - 8192] * S;
    else               v = scl[k - 8704] * LOG2E;
    bws[k] = v;
  }
}

__global__ __launch_bounds__(NTHREADS, 3) void flow_kernel(
    const float* __restrict__ x,
    const f16* __restrict__ wS1p, const f16* __restrict__ wS2, const f16* __restrict__ wS3p,
    const f16* __restrict__ wT1p, const f16* __restrict__ wT2, const f16* __restrict__ wT3p,
    const float* __restrict__ bws, const float* __restrict__ tb3,
    float* __restrict__ y_out, float* __restrict__ ld_out)
{
  __shared__ __attribute__((aligned(16))) f16 act [BM * ACT_S];   // 33792 B
  __shared__ __attribute__((aligned(16))) f16 xm_p[BM * XMP_S];   //  5120 B
  float* ld_red = (float*)xm_p;  // aliased: xm dead by the time logdet reduces

  const int tid  = threadIdx.x;
  const int lane = tid & 63;
  const int wv   = tid >> 6;        // wave: H-quarter (mm1/mm2); (jt,np) for mm3
  const int quad = lane >> 4;
  const int l16  = lane & 15;
  const int row0 = blockIdx.x * BM;
  const int jt   = wv & 1;          // mm3 packed-j tile (16 rows)
  const int np   = wv >> 1;         // mm3 batch half (32 rows)
  const int j0   = jt * 16 + quad * 4;   // this lane's packed-j base

  // Parity-split state in mm3 C-layout: value (j=j0+r, b=np*32+n2*16+l16);
  // global d = 2j (yE), 2j+1 (yO).
  float yE[2][4], yO[2][4];
  float s3r[2][4];   // s-net output * log2e (packed space), regs across nets
  float lda[2];      // logdet partial per n2, accumulated in log2 domain
  lda[0] = 0.f; lda[1] = 0.f;

  #pragma unroll
  for (int n2 = 0; n2 < 2; ++n2) {
    const size_t base = (size_t)(row0 + np * 32 + n2 * 16 + l16) * DIM + 2 * j0;
    const float4 v0 = *(const float4*)&x[base];
    const float4 v1 = *(const float4*)&x[base + 4];
    yE[n2][0] = v0.x; yO[n2][0] = v0.y; yE[n2][1] = v0.z; yO[n2][1] = v0.w;
    yE[n2][2] = v1.x; yO[n2][2] = v1.y; yE[n2][3] = v1.z; yO[n2][3] = v1.w;
  }

  // layer-0 xm = yE (active = even d), straight pk4 into packed cols j0..j0+3
  #pragma unroll
  for (int n2 = 0; n2 < 2; ++n2)
    *(f16x4*)&xm_p[(np * 32 + n2 * 16 + l16) * XMP_S + j0] =
        pk4(yE[n2][0], yE[n2][1], yE[n2][2], yE[n2][3]);
  __syncthreads();                                     // (1) xm ready

  #pragma unroll 1
  for (int l = 0; l < NLAYER; ++l) {
    const int par = l & 1;   // 0: active = even d (yE); 1: active = odd (yO)

    #pragma unroll 1
    for (int net = 0; net < 2; ++net) {
      const f16*   W1 = (net ? wT1p : wS1p) + l * HID * 32;
      const f16*   W2 = (net ? wT2  : wS2)  + l * HID * HID;
      const f16*   W3 = (net ? wT3p : wS3p) + l * 32 * HID;
      const float* b1 = bws + (net ? 2048 : 0) + l * HID;          // *2log2e
      const float* b2 = bws + 4096 + (net ? 2048 : 0) + l * HID;   // *2log2e
      const float* b3 = net ? (tb3 + l * DIM) : (bws + 8192 + l * DIM);

      f32x4 acc[4][4];   // [m = hidden tile][n = batch tile]

      // ---- mm1 (transposed, K=32 packed): C[h,b] = W1p @ xmp^T, C-init = b1 ----
      #pragma unroll
      for (int m = 0; m < 4; ++m) {
        const float4 bv = *(const float4*)&b1[wv * 64 + m * 16 + quad * 4];
        f32x4 bi; bi[0] = bv.x; bi[1] = bv.y; bi[2] = bv.z; bi[3] = bv.w;
        #pragma unroll
        for (int n = 0; n < 4; ++n) acc[m][n] = bi;
      }
      {
        f16x8 afr[4];
        #pragma unroll
        for (int m = 0; m < 4; ++m)
          afr[m] = *(const f16x8*)&W1[(wv * 64 + m * 16 + l16) * 32 + quad * 8];
        __builtin_amdgcn_s_setprio(1);
        #pragma unroll
        for (int n = 0; n < 4; ++n) {
          const f16x8 bfr = *(const f16x8*)&xm_p[(n * 16 + l16) * XMP_S + quad * 8];
          #pragma unroll
          for (int m = 0; m < 4; ++m)
            acc[m][n] = __builtin_amdgcn_mfma_f32_16x16x32_f16(afr[m], bfr, acc[m][n], 0, 0, 0);
        }
        __builtin_amdgcn_s_setprio(0);
      }
      // ep1: act[b, h..h+3] = tanh_pre(acc)  (scale+bias pre-folded)
      #pragma unroll
      for (int m = 0; m < 4; ++m) {
        const int h0 = wv * 64 + m * 16 + quad * 4;
        #pragma unroll
        for (int n = 0; n < 4; ++n)
          *(f16x4*)&act[(n * 16 + l16) * ACT_S + h0] =
              pk4(tanh_pre(acc[m][n][0]), tanh_pre(acc[m][n][1]),
                  tanh_pre(acc[m][n][2]), tanh_pre(acc[m][n][3]));
      }
      __syncthreads();                                   // (2) h1 ready

      // ---- mm2 (transposed): (2log2e*(W2+I)) @ h1^T, C-init = b2 ----
      #pragma unroll
      for (int m = 0; m < 4; ++m) {
        const float4 bv = *(const float4*)&b2[wv * 64 + m * 16 + quad * 4];
        f32x4 bi; bi[0] = bv.x; bi[1] = bv.y; bi[2] = bv.z; bi[3] = bv.w;
        #pragma unroll
        for (int n = 0; n < 4; ++n) acc[m][n] = bi;
      }
      __builtin_amdgcn_s_setprio(1);
      #pragma unroll 2
      for (int kt = 0; kt < 8; ++kt) {
        const int k0 = kt * 32 + quad * 8;
        f16x8 afr[4];
        #pragma unroll
        for (int m = 0; m < 4; ++m)
          afr[m] = *(const f16x8*)&W2[(wv * 64 + m * 16 + l16) * HID + k0];
        #pragma unroll
        for (int n = 0; n < 4; ++n) {
          const f16x8 bfr = *(const f16x8*)&act[(n * 16 + l16) * ACT_S + k0];
          #pragma unroll
          for (int m = 0; m < 4; ++m)
            acc[m][n] = __builtin_amdgcn_mfma_f32_16x16x32_f16(afr[m], bfr, acc[m][n], 0, 0, 0);
        }
      }
      __builtin_amdgcn_s_setprio(0);
      __syncthreads();                                   // (3) all done reading act
      #pragma unroll
      for (int m = 0; m < 4; ++m) {
        const int h0 = wv * 64 + m * 16 + quad * 4;
        #pragma unroll
        for (int n = 0; n < 4; ++n)
          *(f16x4*)&act[(n * 16 + l16) * ACT_S + h0] =
              pk4(tanh_pre(acc[m][n][0]), tanh_pre(acc[m][n][1]),
                  tanh_pre(acc[m][n][2]), tanh_pre(acc[m][n][3]));
      }
      __syncthreads();                                   // (4) h2 ready

      // ---- mm3 (packed rows): C[j,b] = W3p @ h2^T, C-init = b3[inactive] ----
      f32x4 acc3[2];   // [n2]
      {
        const int dj = 2 * j0 + 1 - par;   // global d of packed row j0
        f32x4 bi;
        bi[0] = b3[dj]; bi[1] = b3[dj + 2]; bi[2] = b3[dj + 4]; bi[3] = b3[dj + 6];
        acc3[0] = bi; acc3[1] = bi;
      }
      __builtin_amdgcn_s_setprio(1);
      #pragma unroll 2
      for (int kt = 0; kt < 8; ++kt) {
        const int k0  = kt * 32 + quad * 8;
        const f16x8 a3 = *(const f16x8*)&W3[(jt * 16 + l16) * HID + k0];
        #pragma unroll
        for (int n2 = 0; n2 < 2; ++n2) {
          const f16x8 bfr = *(const f16x8*)&act[(np * 32 + n2 * 16 + l16) * ACT_S + k0];
          acc3[n2] = __builtin_amdgcn_mfma_f32_16x16x32_f16(a3, bfr, acc3[n2], 0, 0, 0);
        }
      }
      __builtin_amdgcn_s_setprio(0);
      if (net == 0) __syncthreads();   // (5) act free for net1's ep1
      // net1's post-mm3 overwrite of act is guarded by next layer's barrier (1)

      if (net == 0) {
        // s3r = tanh(s-net out) * scl * log2e  (scl*log2e staged in bws);
        // stays in regs (same lane in net1).
        const float* scp = bws + 8704 + l * DIM;
        const int dj = 2 * j0 + 1 - par;
        const float sc0 = scp[dj];
        const float sc1 = scp[dj + 2];
        const float sc2 = scp[dj + 4];
        const float sc3 = scp[dj + 6];
        #pragma unroll
        for (int n2 = 0; n2 < 2; ++n2) {
          s3r[n2][0] = tanh_pre(acc3[n2][0]) * sc0;
          s3r[n2][1] = tanh_pre(acc3[n2][1]) * sc1;
          s3r[n2][2] = tanh_pre(acc3[n2][2]) * sc2;
          s3r[n2][3] = tanh_pre(acc3[n2][3]) * sc3;
        }
      } else {
        // ep3: update the INACTIVE state array, lane-local.
        //   y' = y*2^(s*log2e) + (acc3 + b3);  lda accumulates s*log2e
        //   (single *ln2 at the final write).
        #define EP3U(Y)                                                  \
          _Pragma("unroll")                                              \
          for (int n2 = 0; n2 < 2; ++n2) {                               \
            _Pragma("unroll")                                            \
            for (int r = 0; r < 4; ++r) {                                \
              const float s = s3r[n2][r];                                \
              const float e = __builtin_amdgcn_exp2f(s);                 \
              Y[n2][r] = Y[n2][r] * e + acc3[n2][r];                     \
              lda[n2] += s;                                              \
            }                                                            \
          }
        if (par == 0) { EP3U(yO) } else { EP3U(yE) }
        #undef EP3U
      }
    } // net

    if (l + 1 < NLAYER) {
      // xm for layer l+1 = active state of l+1: even layer -> yE, odd -> yO.
      if (((l + 1) & 1) == 0) {
        #pragma unroll
        for (int n2 = 0; n2 < 2; ++n2)
          *(f16x4*)&xm_p[(np * 32 + n2 * 16 + l16) * XMP_S + j0] =
              pk4(yE[n2][0], yE[n2][1], yE[n2][2], yE[n2][3]);
      } else {
        #pragma unroll
        for (int n2 = 0; n2 < 2; ++n2)
          *(f16x4*)&xm_p[(np * 32 + n2 * 16 + l16) * XMP_S + j0] =
              pk4(yO[n2][0], yO[n2][1], yO[n2][2], yO[n2][3]);
      }
    }
    __syncthreads();              // xm ready / final: pre-reduction fence
  } // layers

  // y out: interleave yE/yO in registers -> 2 dwordx4 per n2.
  #pragma unroll
  for (int n2 = 0; n2 < 2; ++n2) {
    const size_t base = (size_t)(row0 + np * 32 + n2 * 16 + l16) * DIM + 2 * j0;
    float4 v0, v1;
    v0.x = yE[n2][0]; v0.y = yO[n2][0]; v0.z = yE[n2][1]; v0.w = yO[n2][1];
    v1.x = yE[n2][2]; v1.y = yO[n2][2]; v1.z = yE[n2][3]; v1.w = yO[n2][3];
    *(float4*)&y_out[base]     = v0;
    *(float4*)&y_out[base + 4] = v1;
  }

  // logdet: lda[n2] covers this lane's 4 j-rows (log2 domain); reduce over
  // quad (shfl), then across the 2 jt-waves of this np-half via LDS.
  float v0 = lda[0], v1 = lda[1];
  v0 += __shfl_xor(v0, 16); v0 += __shfl_xor(v0, 32);
  v1 += __shfl_xor(v1, 16); v1 += __shfl_xor(v1, 32);
  if (quad == 0) {
    ld_red[(np * 32 +      l16) * 2 + jt] = v0;
    ld_red[(np * 32 + 16 + l16) * 2 + jt] = v1;
  }
  __syncthreads();
  if (tid < BM)
    ld_out[row0 + tid] = (ld_red[tid * 2 + 0] + ld_red[tid * 2 + 1]) * LN2;
}

extern "C" void kernel_launch(void* const* d_in, const int* in_sizes, int n_in,
                              void* d_out, int out_size, void* d_ws, size_t ws_size,
                              hipStream_t stream) {
  const float* x     = (const float*)d_in[0];
  const float* sW1f  = (const float*)d_in[2];
  const float* sb1   = (const float*)d_in[3];
  const float* sW2f  = (const float*)d_in[4];
  const float* sb2   = (const float*)d_in[5];
  const float* sW3f  = (const float*)d_in[6];
  const float* sb3   = (const float*)d_in[7];
  const float* scl   = (const float*)d_in[8];
  const float* tW1f  = (const float*)d_in[9];
  const float* tb1   = (const float*)d_in[10];
  const float* tW2f  = (const float*)d_in[11];
  const float* tb2   = (const float*)d_in[12];
  const float* tW3f  = (const float*)d_in[13];
  const float* tb3   = (const float*)d_in[14];
  (void)in_sizes; (void)n_in; (void)out_size; (void)ws_size;

  const int W1PSZ = NLAYER * HID * 32;    // 65536  (column-parity-packed)
  const int W2SZ  = NLAYER * HID * HID;   // 524288
  const int W3PSZ = NLAYER * 32 * HID;    // 65536  (row-parity-packed)
  f16* wS1p = (f16*)d_ws;
  f16* wS2  = wS1p + W1PSZ;
  f16* wS3p = wS2 + W2SZ;
  f16* wT1p = wS3p + W3PSZ;
  f16* wT2  = wT1p + W1PSZ;
  f16* wT3p = wT2 + W2SZ;
  float* bws = (float*)(wT3p + W3PSZ);    // 9216 fp32: scaled biases + scl

  // single cvt pass: 369,664 work items -> 1444 blocks x 256
  cvt_all_kernel<<<1444, 256, 0, stream>>>(
      sW1f, sW2f, sW3f, tW1f, tW2f, tW3f,
      sb1, sb2, sb3, tb1, tb2, scl,
      wS1p, wS2, wS3p, wT1p, wT2, wT3p, bws);

  float* y_out  = (float*)d_out;
  float* ld_out = y_out + (size_t)BATCH * DIM;
  flow_kernel<<<BATCH / BM, NTHREADS, 0, stream>>>(
      x, wS1p, wS2, wS3p, wT1p, wT2, wT3p, bws, tb3, y_out, ld_out);
}